// Round 1
// baseline (463.286 us; speedup 1.0000x reference)
//
#include <hip/hip_runtime.h>
#include <cstddef>
#include <cstdint>

// Problem constants
#define BATCH 8
#define NQ    2048
#define NKV   2048
#define DIN   1024
#define HD    256

typedef __attribute__((ext_vector_type(8))) short bf16x8;
typedef __attribute__((ext_vector_type(4))) float f32x4;

__device__ __forceinline__ float sigmoidf_(float x) {
    return 1.0f / (1.0f + expf(-x));
}

// fp32 -> bf16 round-to-nearest-even
__device__ __forceinline__ unsigned short f2bf(float f) {
    union { float f; unsigned int u; } v;
    v.f = f;
    unsigned int u = v.u;
    return (unsigned short)((u + 0x7FFFu + ((u >> 16) & 1u)) >> 16);
}

// async global->LDS, 16 B per lane; lds base must be wave-uniform
#define GLL16(gp, lp)                                                        \
    __builtin_amdgcn_global_load_lds(                                        \
        (const __attribute__((address_space(1))) void*)(gp),                 \
        (__attribute__((address_space(3))) void*)(lp), 16, 0, 0)

// ---------------------------------------------------------------------------
// Weight prep: w [DIN][HD] fp32  ->  wT [HD][DIN] bf16   (3 weights via z)
// ---------------------------------------------------------------------------
__global__ __launch_bounds__(256)
void wtrans_kernel(const float* __restrict__ w0, const float* __restrict__ w1,
                   const float* __restrict__ w2,
                   unsigned short* __restrict__ t0, unsigned short* __restrict__ t1,
                   unsigned short* __restrict__ t2)
{
    const float* w = (blockIdx.z == 0) ? w0 : (blockIdx.z == 1) ? w1 : w2;
    unsigned short* t = (blockIdx.z == 0) ? t0 : (blockIdx.z == 1) ? t1 : t2;
    const int k0 = blockIdx.y * 64;
    const int n0 = blockIdx.x * 64;
    const int tid = threadIdx.x;
    const int kq = tid >> 4;
    const int nq = tid & 15;
    float4 r[4];
#pragma unroll
    for (int i = 0; i < 4; ++i)
        r[i] = *(const float4*)&w[(size_t)(k0 + kq * 4 + i) * HD + n0 + nq * 4];
#pragma unroll
    for (int j = 0; j < 4; ++j) {
        ushort4 o;
        o.x = f2bf(((const float*)&r[0])[j]);
        o.y = f2bf(((const float*)&r[1])[j]);
        o.z = f2bf(((const float*)&r[2])[j]);
        o.w = f2bf(((const float*)&r[3])[j]);
        *(ushort4*)&t[(size_t)(n0 + nq * 4 + j) * DIN + k0 + kq * 4] = o;
    }
}

// ---------------------------------------------------------------------------
// Shared tiling: 32(m) x 256(n full) x 32(k). 4 waves; wave w owns the
// 64-wide h-strip [w*64, w*64+64) for all 32 m-rows.
// TS=32 (was 64): doubles the grid to 512 blocks -> 2 blocks/CU
// (LDS/block ~70 KB, two fit in 160 KB) -> 8 waves/CU. The previous
// 256-block grid pinned occupancy at 1 block/CU = 1 wave/SIMD, fully
// exposing every vmcnt-drain + barrier (MfmaUtil 12.7%, HBM 19%).
// A: padded LDS (stride 40), staged via regular ds_write.
// B: unpadded [256*32], staged via global_load_lds with chunk-XOR swizzle
//    (chunk c of row holds global k-chunk c ^ ((row>>1)&3)) -> frag reads 2-way.
// Ping-pong buffers, ONE __syncthreads per k-iter phase.
// ---------------------------------------------------------------------------
#define TS 32
#define TH 256
#define TK 32
#define A_LD 40

// ---------------------------------------------------------------------------
// Q projection: sigQ = sigmoid(x_q @ wq + b)   [16384,1024]@[1024,256]
// ---------------------------------------------------------------------------
__global__ __launch_bounds__(256, 2)
void proj_q_mfma(const float* __restrict__ X,
                 const unsigned short* __restrict__ WT,  // [HD][DIN]
                 const float* __restrict__ bv,
                 float* __restrict__ sigQ)
{
    __shared__ unsigned short As[2][TS][A_LD];
    __shared__ unsigned short Bs[2][TH * TK];

    const int m0 = blockIdx.x * TS;
    const int tid = threadIdx.x;
    const int lane = tid & 63, wave = tid >> 6;
    const int quad = lane >> 4, l16 = lane & 15;

    const int a_row = tid >> 3, a_koff = (tid & 7) * 4;
    const float* aP = X + (size_t)(m0 + a_row) * DIN + a_koff;

    const unsigned short* bP[4];
    int ldsOff[4];
#pragma unroll
    for (int j = 0; j < 4; ++j) {
        int idx = j * 256 + tid;
        int row = idx >> 2, c = idx & 3;
        int kc = c ^ ((row >> 1) & 3);
        bP[j] = WT + (size_t)row * DIN + kc * 8;
        ldsOff[j] = (j * 256 + wave * 64) * 16;
    }

    f32x4 acc[2][4] = {};
    float4 a0 = *(const float4*)aP;

    for (int k0 = 0; k0 < DIN; k0 += TK) {
        const int p = (k0 >> 5) & 1;
        ushort4 q0;
        q0.x = f2bf(a0.x); q0.y = f2bf(a0.y); q0.z = f2bf(a0.z); q0.w = f2bf(a0.w);
        *(ushort4*)&As[p][a_row][a_koff] = q0;
        char* bL = (char*)&Bs[p][0];
#pragma unroll
        for (int j = 0; j < 4; ++j)
            GLL16(bP[j] + k0, bL + ldsOff[j]);
        __syncthreads();
        if (k0 + TK < DIN)
            a0 = *(const float4*)(aP + k0 + TK);
        bf16x8 af[2], bf[4];
#pragma unroll
        for (int rt = 0; rt < 2; ++rt)
            af[rt] = *(const bf16x8*)&As[p][rt * 16 + l16][quad * 8];
#pragma unroll
        for (int ct = 0; ct < 4; ++ct) {
            int row = wave * 64 + ct * 16 + l16;
            int off = row * 64 + ((quad ^ ((row >> 1) & 3)) * 16);
            bf[ct] = *(const bf16x8*)((const char*)&Bs[p][0] + off);
        }
#pragma unroll
        for (int rt = 0; rt < 2; ++rt)
#pragma unroll
            for (int ct = 0; ct < 4; ++ct)
                acc[rt][ct] = __builtin_amdgcn_mfma_f32_16x16x32_bf16(
                    af[rt], bf[ct], acc[rt][ct], 0, 0, 0);
        __syncthreads();
    }

#pragma unroll
    for (int rt = 0; rt < 2; ++rt)
#pragma unroll
        for (int ct = 0; ct < 4; ++ct) {
            const int h = wave * 64 + ct * 16 + l16;
            const float bb = bv[h];
#pragma unroll
            for (int r = 0; r < 4; ++r) {
                const int m = m0 + rt * 16 + quad * 4 + r;
                sigQ[(size_t)m * HD + h] = sigmoidf_(acc[rt][ct][r] + bb);
            }
        }
}

// ---------------------------------------------------------------------------
// K/V projection (dual B, shared A): outputs bf16, transposed [B][HD][NKV]
// ---------------------------------------------------------------------------
__global__ __launch_bounds__(256, 2)
void proj_kv_mfma(const float* __restrict__ X,
                  const unsigned short* __restrict__ WKT,
                  const float* __restrict__ bk,
                  const unsigned short* __restrict__ WVT,
                  const float* __restrict__ bvv,
                  unsigned short* __restrict__ eKt,
                  unsigned short* __restrict__ eKVt)
{
    __shared__ unsigned short As[2][TS][A_LD];
    __shared__ unsigned short Bk[2][TH * TK];
    __shared__ unsigned short Bv[2][TH * TK];

    const int m0 = blockIdx.x * TS;
    const int tid = threadIdx.x;
    const int lane = tid & 63, wave = tid >> 6;
    const int quad = lane >> 4, l16 = lane & 15;

    const int a_row = tid >> 3, a_koff = (tid & 7) * 4;
    const float* aP = X + (size_t)(m0 + a_row) * DIN + a_koff;

    const unsigned short* bkP[4];
    const unsigned short* bvP[4];
    int ldsOff[4];
#pragma unroll
    for (int j = 0; j < 4; ++j) {
        int idx = j * 256 + tid;
        int row = idx >> 2, c = idx & 3;
        int kc = c ^ ((row >> 1) & 3);
        bkP[j] = WKT + (size_t)row * DIN + kc * 8;
        bvP[j] = WVT + (size_t)row * DIN + kc * 8;
        ldsOff[j] = (j * 256 + wave * 64) * 16;
    }

    f32x4 acck[2][4] = {};
    f32x4 accv[2][4] = {};
    float4 a0 = *(const float4*)aP;

    for (int k0 = 0; k0 < DIN; k0 += TK) {
        const int p = (k0 >> 5) & 1;
        ushort4 q0;
        q0.x = f2bf(a0.x); q0.y = f2bf(a0.y); q0.z = f2bf(a0.z); q0.w = f2bf(a0.w);
        *(ushort4*)&As[p][a_row][a_koff] = q0;
        char* bkL = (char*)&Bk[p][0];
        char* bvL = (char*)&Bv[p][0];
#pragma unroll
        for (int j = 0; j < 4; ++j) {
            GLL16(bkP[j] + k0, bkL + ldsOff[j]);
            GLL16(bvP[j] + k0, bvL + ldsOff[j]);
        }
        __syncthreads();
        if (k0 + TK < DIN)
            a0 = *(const float4*)(aP + k0 + TK);
        bf16x8 af[2], bkf[4], bvf[4];
#pragma unroll
        for (int rt = 0; rt < 2; ++rt)
            af[rt] = *(const bf16x8*)&As[p][rt * 16 + l16][quad * 8];
#pragma unroll
        for (int ct = 0; ct < 4; ++ct) {
            int row = wave * 64 + ct * 16 + l16;
            int off = row * 64 + ((quad ^ ((row >> 1) & 3)) * 16);
            bkf[ct] = *(const bf16x8*)((const char*)&Bk[p][0] + off);
            bvf[ct] = *(const bf16x8*)((const char*)&Bv[p][0] + off);
        }
#pragma unroll
        for (int rt = 0; rt < 2; ++rt)
#pragma unroll
            for (int ct = 0; ct < 4; ++ct) {
                acck[rt][ct] = __builtin_amdgcn_mfma_f32_16x16x32_bf16(
                    af[rt], bkf[ct], acck[rt][ct], 0, 0, 0);
                accv[rt][ct] = __builtin_amdgcn_mfma_f32_16x16x32_bf16(
                    af[rt], bvf[ct], accv[rt][ct], 0, 0, 0);
            }
        __syncthreads();
    }

    const int bidx = m0 >> 11;
    const int tb = m0 & (NKV - 1);
#pragma unroll
    for (int rt = 0; rt < 2; ++rt)
#pragma unroll
        for (int ct = 0; ct < 4; ++ct) {
            const int h = wave * 64 + ct * 16 + l16;
            const float bkb = bk[h];
            const float bvb = bvv[h];
            ushort4 pk, pv;
            unsigned short* pK = (unsigned short*)&pk;
            unsigned short* pV = (unsigned short*)&pv;
#pragma unroll
            for (int r = 0; r < 4; ++r) {
                float e  = __expf(acck[rt][ct][r] + bkb);
                float ev = e * (accv[rt][ct][r] + bvb);
                pK[r] = f2bf(e);
                pV[r] = f2bf(ev);
            }
            const int t0 = tb + rt * 16 + quad * 4;
            size_t base = ((size_t)bidx * HD + h) * NKV + t0;
            *(ushort4*)&eKt[base]  = pk;
            *(ushort4*)&eKVt[base] = pv;
        }
}

// ---------------------------------------------------------------------------
// Core AFT einsum: full-H tile, exp(bias) staged once, dual B via gll.
//   Yt[s,h] = sigQ * (exp(bias)@expKV) / (exp(bias)@expK)
// Block swizzle: batch = linear_block_id % 8 so each XCD (round-robin
// dispatch) owns exactly one batch -> its 2 MB of eKt/eKVt is resident
// in that XCD's private 4 MB L2 instead of bouncing through L3.
// ---------------------------------------------------------------------------
__global__ __launch_bounds__(256, 2)
void aft_mfma_kernel(const float* __restrict__ bias,
                     const unsigned short* __restrict__ eKt,    // [B][HD][NKV]
                     const unsigned short* __restrict__ eKVt,   // [B][HD][NKV]
                     const float* __restrict__ sigQ,
                     float* __restrict__ Yt)
{
    __shared__ unsigned short As[2][TS][A_LD];
    __shared__ unsigned short Bn[2][TH * TK];
    __shared__ unsigned short Bd[2][TH * TK];

    const int lin = blockIdx.y * gridDim.x + blockIdx.x;  // 0..511
    const int b   = lin & 7;                              // batch == XCD id
    const int s0  = (lin >> 3) * TS;
    const int tid = threadIdx.x;
    const int lane = tid & 63, wave = tid >> 6;
    const int quad = lane >> 4, l16 = lane & 15;

    const int a_row = tid >> 3, a_koff = (tid & 7) * 4;
    const float* aP = bias + ((size_t)b * NQ + (s0 + a_row)) * NKV + a_koff;

    const unsigned short* bnP[4];
    const unsigned short* bdP[4];
    int ldsOff[4];
#pragma unroll
    for (int j = 0; j < 4; ++j) {
        int idx = j * 256 + tid;
        int row = idx >> 2, c = idx & 3;
        int kc = c ^ ((row >> 1) & 3);
        bnP[j] = eKVt + ((size_t)b * HD + row) * NKV + kc * 8;
        bdP[j] = eKt  + ((size_t)b * HD + row) * NKV + kc * 8;
        ldsOff[j] = (j * 256 + wave * 64) * 16;
    }

    f32x4 accn[2][4] = {};
    f32x4 accd[2][4] = {};
    float4 a0 = *(const float4*)aP;

    for (int k0 = 0; k0 < NKV; k0 += TK) {
        const int p = (k0 >> 5) & 1;
        ushort4 q0;
        q0.x = f2bf(__expf(a0.x)); q0.y = f2bf(__expf(a0.y));
        q0.z = f2bf(__expf(a0.z)); q0.w = f2bf(__expf(a0.w));
        *(ushort4*)&As[p][a_row][a_koff] = q0;
        char* bnL = (char*)&Bn[p][0];
        char* bdL = (char*)&Bd[p][0];
#pragma unroll
        for (int j = 0; j < 4; ++j) {
            GLL16(bnP[j] + k0, bnL + ldsOff[j]);
            GLL16(bdP[j] + k0, bdL + ldsOff[j]);
        }
        __syncthreads();
        if (k0 + TK < NKV)
            a0 = *(const float4*)(aP + k0 + TK);
        bf16x8 af[2], bnf[4], bdf[4];
#pragma unroll
        for (int rt = 0; rt < 2; ++rt)
            af[rt] = *(const bf16x8*)&As[p][rt * 16 + l16][quad * 8];
#pragma unroll
        for (int ct = 0; ct < 4; ++ct) {
            int row = wave * 64 + ct * 16 + l16;
            int off = row * 64 + ((quad ^ ((row >> 1) & 3)) * 16);
            bnf[ct] = *(const bf16x8*)((const char*)&Bn[p][0] + off);
            bdf[ct] = *(const bf16x8*)((const char*)&Bd[p][0] + off);
        }
#pragma unroll
        for (int rt = 0; rt < 2; ++rt)
#pragma unroll
            for (int ct = 0; ct < 4; ++ct) {
                accn[rt][ct] = __builtin_amdgcn_mfma_f32_16x16x32_bf16(
                    af[rt], bnf[ct], accn[rt][ct], 0, 0, 0);
                accd[rt][ct] = __builtin_amdgcn_mfma_f32_16x16x32_bf16(
                    af[rt], bdf[ct], accd[rt][ct], 0, 0, 0);
            }
        __syncthreads();
    }

#pragma unroll
    for (int rt = 0; rt < 2; ++rt)
#pragma unroll
        for (int ct = 0; ct < 4; ++ct) {
            const int h = wave * 64 + ct * 16 + l16;
#pragma unroll
            for (int r = 0; r < 4; ++r) {
                const int s = s0 + rt * 16 + quad * 4 + r;
                const size_t idx = ((size_t)b * NQ + s) * HD + h;
                Yt[idx] = sigQ[idx] * accn[rt][ct][r] / accd[rt][ct][r];
            }
        }
}

// ---------------------------------------------------------------------------
// Final fp32 GEMM: out = Yt @ f2_w + f2_b   [16384,256]@[256,256]
// ---------------------------------------------------------------------------
#define BM 64
#define BN 64
#define BK 16
#define PADF 4
#define LDAF (BM + PADF)
#define LDBF (BN + PADF)

__global__ __launch_bounds__(256)
void gemm_bias_kernel(const float* __restrict__ X, const float* __restrict__ W,
                      const float* __restrict__ bv, float* __restrict__ out,
                      int M, int N, int K)
{
    __shared__ float As[BK][LDAF];
    __shared__ float Ws[BK][LDBF];
    const int tid = threadIdx.x;
    const int tx = tid & 15, ty = tid >> 4;
    const int row0 = blockIdx.y * BM;
    const int col0 = blockIdx.x * BN;
    const int la_row = tid >> 2, la_col = (tid & 3) * 4;
    const int lw_row = tid >> 4, lw_col = (tid & 15) * 4;

    float acc[4][4] = {};

    const float* Xp = X + (size_t)(row0 + la_row) * K + la_col;
    const float* Wp = W + (size_t)lw_row * N + col0 + lw_col;

    for (int k0 = 0; k0 < K; k0 += BK) {
        float4 av = *(const float4*)(Xp + k0);
        float4 wv = *(const float4*)(Wp + (size_t)k0 * N);
        As[la_col + 0][la_row] = av.x;
        As[la_col + 1][la_row] = av.y;
        As[la_col + 2][la_row] = av.z;
        As[la_col + 3][la_row] = av.w;
        *(float4*)&Ws[lw_row][lw_col] = wv;
        __syncthreads();
#pragma unroll
        for (int kk = 0; kk < BK; ++kk) {
            float4 a4 = *(const float4*)&As[kk][ty * 4];
            float4 w4 = *(const float4*)&Ws[kk][tx * 4];
            float aa[4] = {a4.x, a4.y, a4.z, a4.w};
            float ww[4] = {w4.x, w4.y, w4.z, w4.w};
#pragma unroll
            for (int i = 0; i < 4; ++i)
#pragma unroll
                for (int j = 0; j < 4; ++j)
                    acc[i][j] = fmaf(aa[i], ww[j], acc[i][j]);
        }
        __syncthreads();
    }

    float bb[4];
#pragma unroll
    for (int j = 0; j < 4; ++j) bb[j] = bv[col0 + tx * 4 + j];
#pragma unroll
    for (int i = 0; i < 4; ++i) {
        int r = row0 + ty * 4 + i;
        float4 o;
        o.x = acc[i][0] + bb[0];
        o.y = acc[i][1] + bb[1];
        o.z = acc[i][2] + bb[2];
        o.w = acc[i][3] + bb[3];
        *(float4*)&out[(size_t)r * N + col0 + tx * 4] = o;
    }
}

extern "C" void kernel_launch(void* const* d_in, const int* in_sizes, int n_in,
                              void* d_out, int out_size, void* d_ws, size_t ws_size,
                              hipStream_t stream)
{
    const float* x_q  = (const float*)d_in[0];
    const float* x_kv = (const float*)d_in[1];
    const float* bias = (const float*)d_in[2];
    const float* wq_w = (const float*)d_in[3];
    const float* wq_b = (const float*)d_in[4];
    const float* wk_w = (const float*)d_in[5];
    const float* wk_b = (const float*)d_in[6];
    const float* wv_w = (const float*)d_in[7];
    const float* wv_b = (const float*)d_in[8];
    const float* f2_w = (const float*)d_in[9];
    const float* f2_b = (const float*)d_in[10];
    float* out = (float*)d_out;

    // Workspace: sigQ fp32 | Yt fp32 | eKt bf16 | eKVt bf16 | wqT|wkT|wvT bf16
    float* ws = (float*)d_ws;
    const size_t nBH = (size_t)BATCH * NQ * HD;       // 4,194,304
    float* sigQ = ws;
    float* Yt   = ws + nBH;
    unsigned short* eKt  = (unsigned short*)(ws + 2 * nBH);
    unsigned short* eKVt = eKt + nBH;
    unsigned short* wqT  = eKVt + nBH;
    unsigned short* wkT  = wqT + (size_t)HD * DIN;
    unsigned short* wvT  = wkT + (size_t)HD * DIN;

    const int M = BATCH * NQ;   // 16384
    dim3 blk(256);

    // 0) transpose+convert weights to bf16 [HD][DIN]
    wtrans_kernel<<<dim3(HD / 64, DIN / 64, 3), blk, 0, stream>>>(
        wq_w, wk_w, wv_w, wqT, wkT, wvT);

    // 1) sigQ = sigmoid(x_q @ wq + b)   (512 blocks -> 2/CU)
    proj_q_mfma<<<dim3(M / TS), blk, 0, stream>>>(x_q, wqT, wq_b, sigQ);

    // 2) eKt/eKVt (bf16, transposed) from x_kv   (512 blocks -> 2/CU)
    proj_kv_mfma<<<dim3(M / TS), blk, 0, stream>>>(
        x_kv, wkT, wk_b, wvT, wv_b, eKt, eKVt);

    // 3) Yt = sigQ * (exp(bias)@expKV)/(exp(bias)@expK)   (512 blocks -> 2/CU)
    aft_mfma_kernel<<<dim3(NQ / TS, BATCH), blk, 0, stream>>>(
        bias, eKt, eKVt, sigQ, Yt);

    // 4) out = Yt @ f2_w + f2_b  (fp32, precision guard)
    gemm_bias_kernel<<<dim3(HD / BN, M / BM), blk, 0, stream>>>(
        Yt, f2_w, f2_b, out, M, HD, HD);
}

// Round 2
// 456.741 us; speedup vs baseline: 1.0143x; 1.0143x over previous
//
#include <hip/hip_runtime.h>
#include <cstddef>
#include <cstdint>

// Problem constants
#define BATCH 8
#define NQ    2048
#define NKV   2048
#define DIN   1024
#define HD    256

typedef __attribute__((ext_vector_type(8))) short bf16x8;
typedef __attribute__((ext_vector_type(4))) float f32x4;

__device__ __forceinline__ float sigmoidf_(float x) {
    return 1.0f / (1.0f + expf(-x));
}

// fp32 -> bf16 round-to-nearest-even
__device__ __forceinline__ unsigned short f2bf(float f) {
    union { float f; unsigned int u; } v;
    v.f = f;
    unsigned int u = v.u;
    return (unsigned short)((u + 0x7FFFu + ((u >> 16) & 1u)) >> 16);
}

// async global->LDS, 16 B per lane; lds base must be wave-uniform
#define GLL16(gp, lp)                                                        \
    __builtin_amdgcn_global_load_lds(                                        \
        (const __attribute__((address_space(1))) void*)(gp),                 \
        (__attribute__((address_space(3))) void*)(lp), 16, 0, 0)

// 16B global load via inline asm: keeps vmcnt bookkeeping in OUR hands so the
// compiler never emits its own conservative vmcnt(0) for these results.
__device__ __forceinline__ f32x4 gload4(const float* p) {
    f32x4 r;
    asm volatile("global_load_dwordx4 %0, %1, off"
                 : "=v"(r) : "v"(p) : "memory");
    return r;
}

// ---------------------------------------------------------------------------
// Weight prep: w [DIN][HD] fp32  ->  wT [HD][DIN] bf16   (3 weights via z)
// ---------------------------------------------------------------------------
__global__ __launch_bounds__(256)
void wtrans_kernel(const float* __restrict__ w0, const float* __restrict__ w1,
                   const float* __restrict__ w2,
                   unsigned short* __restrict__ t0, unsigned short* __restrict__ t1,
                   unsigned short* __restrict__ t2)
{
    const float* w = (blockIdx.z == 0) ? w0 : (blockIdx.z == 1) ? w1 : w2;
    unsigned short* t = (blockIdx.z == 0) ? t0 : (blockIdx.z == 1) ? t1 : t2;
    const int k0 = blockIdx.y * 64;
    const int n0 = blockIdx.x * 64;
    const int tid = threadIdx.x;
    const int kq = tid >> 4;
    const int nq = tid & 15;
    float4 r[4];
#pragma unroll
    for (int i = 0; i < 4; ++i)
        r[i] = *(const float4*)&w[(size_t)(k0 + kq * 4 + i) * HD + n0 + nq * 4];
#pragma unroll
    for (int j = 0; j < 4; ++j) {
        ushort4 o;
        o.x = f2bf(((const float*)&r[0])[j]);
        o.y = f2bf(((const float*)&r[1])[j]);
        o.z = f2bf(((const float*)&r[2])[j]);
        o.w = f2bf(((const float*)&r[3])[j]);
        *(ushort4*)&t[(size_t)(n0 + nq * 4 + j) * DIN + k0 + kq * 4] = o;
    }
}

// ---------------------------------------------------------------------------
// Shared tiling: 64(m) x 256(n full) x 32(k). 4 waves; wave w owns the
// 64-wide h-strip [w*64, w*64+64) for all 64 m-rows.  Grid = 256 = 1 blk/CU.
//
// PIPELINED k-loop (T3/T4): next B tile's global_load_lds issued at TOP of
// iter k into buffer p^1; stays in flight across BOTH barriers; drained one
// full iteration later by an explicit counted s_waitcnt (never vmcnt(0) in
// the loop).  A-operand loads use inline-asm gload4 + distance-2 register
// rotation so the compiler never inserts its own conservative drain.
// Raw s_barrier (no compiler vmcnt(0)).
//
// Safety protocol (2 barriers/iter):
//   top:   GLL -> B[pn]            (B[pn] reads finished before prev end-bar)
//   wait vmcnt(#newGLL): c regs ready AND B[p] (issued last iter) landed
//   cvt+ds_write As[p]; issue bias loads (distance 2)
//   lgkmcnt(0)+s_barrier: As[p]/B[p] published, GLLs stay in flight
//   frag reads + MFMA
//   s_barrier: B[pn] safe to have been written; As parity protects A
// ---------------------------------------------------------------------------
#define TS 64
#define TH 256
#define TK 32
#define A_LD 40

// ---------------------------------------------------------------------------
// Q projection: sigQ = sigmoid(x_q @ wq + b)   [16384,1024]@[1024,256]
// ---------------------------------------------------------------------------
__global__ __launch_bounds__(256, 1)
void proj_q_mfma(const float* __restrict__ X,
                 const unsigned short* __restrict__ WT,  // [HD][DIN]
                 const float* __restrict__ bv,
                 float* __restrict__ sigQ)
{
    __shared__ unsigned short As[2][TS][A_LD];
    __shared__ unsigned short Bs[2][TH * TK];

    const int m0 = blockIdx.x * TS;
    const int tid = threadIdx.x;
    const int lane = tid & 63, wave = tid >> 6;
    const int quad = lane >> 4, l16 = lane & 15;

    const int a_row = tid >> 2, a_koff = (tid & 3) * 8;
    const float* aP = X + (size_t)(m0 + a_row) * DIN + a_koff;

    const unsigned short* bP[4];
    int ldsOff[4];
#pragma unroll
    for (int j = 0; j < 4; ++j) {
        int idx = j * 256 + tid;
        int row = idx >> 2, c = idx & 3;
        int kc = c ^ ((row >> 1) & 3);
        bP[j] = WT + (size_t)row * DIN + kc * 8;
        ldsOff[j] = (j * 256 + wave * 64) * 16;
    }

    f32x4 acc[4][4] = {};

    // Prologue: B tile 0 in flight; bias regs distance-2
#pragma unroll
    for (int j = 0; j < 4; ++j)
        GLL16(bP[j], (char*)&Bs[0][0] + ldsOff[j]);
    f32x4 c0 = gload4(aP);
    f32x4 c1 = gload4(aP + 4);
    f32x4 n0 = gload4(aP + TK);
    f32x4 n1 = gload4(aP + TK + 4);

    for (int k0 = 0; k0 < DIN; k0 += TK) {
        const int p = (k0 >> 5) & 1, pn = p ^ 1;
        const int kb = (k0 + TK < DIN) ? (k0 + TK) : (DIN - TK);
        const int km = (k0 + 2 * TK < DIN) ? (k0 + 2 * TK) : (DIN - TK);
        char* bL = (char*)&Bs[pn][0];
#pragma unroll
        for (int j = 0; j < 4; ++j)
            GLL16(bP[j] + kb, bL + ldsOff[j]);
        // c ready + B[p] landed; the 4 GLLs just issued stay in flight
        asm volatile("s_waitcnt vmcnt(4)" : "+v"(c0), "+v"(c1) :: "memory");
        ushort4 q0, q1;
        q0.x = f2bf(c0[0]); q0.y = f2bf(c0[1]); q0.z = f2bf(c0[2]); q0.w = f2bf(c0[3]);
        q1.x = f2bf(c1[0]); q1.y = f2bf(c1[1]); q1.z = f2bf(c1[2]); q1.w = f2bf(c1[3]);
        *(ushort4*)&As[p][a_row][a_koff]     = q0;
        *(ushort4*)&As[p][a_row][a_koff + 4] = q1;
        f32x4 m0v = gload4(aP + km);
        f32x4 m1v = gload4(aP + km + 4);
        asm volatile("s_waitcnt lgkmcnt(0)\ns_barrier" ::: "memory");
        bf16x8 af[4], bf[4];
#pragma unroll
        for (int rt = 0; rt < 4; ++rt)
            af[rt] = *(const bf16x8*)&As[p][rt * 16 + l16][quad * 8];
#pragma unroll
        for (int ct = 0; ct < 4; ++ct) {
            int row = wave * 64 + ct * 16 + l16;
            int off = row * 64 + ((quad ^ ((row >> 1) & 3)) * 16);
            bf[ct] = *(const bf16x8*)((const char*)&Bs[p][0] + off);
        }
#pragma unroll
        for (int rt = 0; rt < 4; ++rt)
#pragma unroll
            for (int ct = 0; ct < 4; ++ct)
                acc[rt][ct] = __builtin_amdgcn_mfma_f32_16x16x32_bf16(
                    af[rt], bf[ct], acc[rt][ct], 0, 0, 0);
        asm volatile("s_barrier" ::: "memory");
        c0 = n0; c1 = n1; n0 = m0v; n1 = m1v;
    }

#pragma unroll
    for (int rt = 0; rt < 4; ++rt)
#pragma unroll
        for (int ct = 0; ct < 4; ++ct) {
            const int h = wave * 64 + ct * 16 + l16;
            const float bb = bv[h];
#pragma unroll
            for (int r = 0; r < 4; ++r) {
                const int m = m0 + rt * 16 + quad * 4 + r;
                sigQ[(size_t)m * HD + h] = sigmoidf_(acc[rt][ct][r] + bb);
            }
        }
}

// ---------------------------------------------------------------------------
// K/V projection (dual B, shared A): outputs bf16, transposed [B][HD][NKV]
// ---------------------------------------------------------------------------
__global__ __launch_bounds__(256, 1)
void proj_kv_mfma(const float* __restrict__ X,
                  const unsigned short* __restrict__ WKT,
                  const float* __restrict__ bk,
                  const unsigned short* __restrict__ WVT,
                  const float* __restrict__ bvv,
                  unsigned short* __restrict__ eKt,
                  unsigned short* __restrict__ eKVt)
{
    __shared__ unsigned short As[2][TS][A_LD];
    __shared__ unsigned short Bk[2][TH * TK];
    __shared__ unsigned short Bv[2][TH * TK];

    const int m0 = blockIdx.x * TS;
    const int tid = threadIdx.x;
    const int lane = tid & 63, wave = tid >> 6;
    const int quad = lane >> 4, l16 = lane & 15;

    const int a_row = tid >> 2, a_koff = (tid & 3) * 8;
    const float* aP = X + (size_t)(m0 + a_row) * DIN + a_koff;

    const unsigned short* bkP[4];
    const unsigned short* bvP[4];
    int ldsOff[4];
#pragma unroll
    for (int j = 0; j < 4; ++j) {
        int idx = j * 256 + tid;
        int row = idx >> 2, c = idx & 3;
        int kc = c ^ ((row >> 1) & 3);
        bkP[j] = WKT + (size_t)row * DIN + kc * 8;
        bvP[j] = WVT + (size_t)row * DIN + kc * 8;
        ldsOff[j] = (j * 256 + wave * 64) * 16;
    }

    f32x4 acck[4][4] = {};
    f32x4 accv[4][4] = {};

#pragma unroll
    for (int j = 0; j < 4; ++j) {
        GLL16(bkP[j], (char*)&Bk[0][0] + ldsOff[j]);
        GLL16(bvP[j], (char*)&Bv[0][0] + ldsOff[j]);
    }
    f32x4 c0 = gload4(aP);
    f32x4 c1 = gload4(aP + 4);
    f32x4 n0 = gload4(aP + TK);
    f32x4 n1 = gload4(aP + TK + 4);

    for (int k0 = 0; k0 < DIN; k0 += TK) {
        const int p = (k0 >> 5) & 1, pn = p ^ 1;
        const int kb = (k0 + TK < DIN) ? (k0 + TK) : (DIN - TK);
        const int km = (k0 + 2 * TK < DIN) ? (k0 + 2 * TK) : (DIN - TK);
        char* bkL = (char*)&Bk[pn][0];
        char* bvL = (char*)&Bv[pn][0];
#pragma unroll
        for (int j = 0; j < 4; ++j) {
            GLL16(bkP[j] + kb, bkL + ldsOff[j]);
            GLL16(bvP[j] + kb, bvL + ldsOff[j]);
        }
        asm volatile("s_waitcnt vmcnt(8)" : "+v"(c0), "+v"(c1) :: "memory");
        ushort4 q0, q1;
        q0.x = f2bf(c0[0]); q0.y = f2bf(c0[1]); q0.z = f2bf(c0[2]); q0.w = f2bf(c0[3]);
        q1.x = f2bf(c1[0]); q1.y = f2bf(c1[1]); q1.z = f2bf(c1[2]); q1.w = f2bf(c1[3]);
        *(ushort4*)&As[p][a_row][a_koff]     = q0;
        *(ushort4*)&As[p][a_row][a_koff + 4] = q1;
        f32x4 m0v = gload4(aP + km);
        f32x4 m1v = gload4(aP + km + 4);
        asm volatile("s_waitcnt lgkmcnt(0)\ns_barrier" ::: "memory");
        bf16x8 af[4], bkf[4], bvf[4];
#pragma unroll
        for (int rt = 0; rt < 4; ++rt)
            af[rt] = *(const bf16x8*)&As[p][rt * 16 + l16][quad * 8];
#pragma unroll
        for (int ct = 0; ct < 4; ++ct) {
            int row = wave * 64 + ct * 16 + l16;
            int off = row * 64 + ((quad ^ ((row >> 1) & 3)) * 16);
            bkf[ct] = *(const bf16x8*)((const char*)&Bk[p][0] + off);
            bvf[ct] = *(const bf16x8*)((const char*)&Bv[p][0] + off);
        }
#pragma unroll
        for (int rt = 0; rt < 4; ++rt)
#pragma unroll
            for (int ct = 0; ct < 4; ++ct) {
                acck[rt][ct] = __builtin_amdgcn_mfma_f32_16x16x32_bf16(
                    af[rt], bkf[ct], acck[rt][ct], 0, 0, 0);
                accv[rt][ct] = __builtin_amdgcn_mfma_f32_16x16x32_bf16(
                    af[rt], bvf[ct], accv[rt][ct], 0, 0, 0);
            }
        asm volatile("s_barrier" ::: "memory");
        c0 = n0; c1 = n1; n0 = m0v; n1 = m1v;
    }

    const int bidx = m0 >> 11;
    const int tb = m0 & (NKV - 1);
#pragma unroll
    for (int rt = 0; rt < 4; ++rt)
#pragma unroll
        for (int ct = 0; ct < 4; ++ct) {
            const int h = wave * 64 + ct * 16 + l16;
            const float bkb = bk[h];
            const float bvb = bvv[h];
            ushort4 pk, pv;
            unsigned short* pK = (unsigned short*)&pk;
            unsigned short* pV = (unsigned short*)&pv;
#pragma unroll
            for (int r = 0; r < 4; ++r) {
                float e  = __expf(acck[rt][ct][r] + bkb);
                float ev = e * (accv[rt][ct][r] + bvb);
                pK[r] = f2bf(e);
                pV[r] = f2bf(ev);
            }
            const int t0 = tb + rt * 16 + quad * 4;
            size_t base = ((size_t)bidx * HD + h) * NKV + t0;
            *(ushort4*)&eKt[base]  = pk;
            *(ushort4*)&eKVt[base] = pv;
        }
}

// ---------------------------------------------------------------------------
// Core AFT einsum: full-H tile, exp(bias) staged once, dual B via gll.
//   Yt[s,h] = sigQ * (exp(bias)@expKV) / (exp(bias)@expK)
// batch = lin & 7 so each XCD (round-robin dispatch) owns one batch ->
// its 2 MB of eKt/eKVt stays in that XCD's private L2 (FETCH 140->82 MB).
// ---------------------------------------------------------------------------
__global__ __launch_bounds__(256, 1)
void aft_mfma_kernel(const float* __restrict__ bias,
                     const unsigned short* __restrict__ eKt,    // [B][HD][NKV]
                     const unsigned short* __restrict__ eKVt,   // [B][HD][NKV]
                     const float* __restrict__ sigQ,
                     float* __restrict__ Yt)
{
    __shared__ unsigned short As[2][TS][A_LD];
    __shared__ unsigned short Bn[2][TH * TK];
    __shared__ unsigned short Bd[2][TH * TK];

    const int lin = blockIdx.y * gridDim.x + blockIdx.x;  // 0..255
    const int b   = lin & 7;                              // batch == XCD id
    const int s0  = (lin >> 3) * TS;
    const int tid = threadIdx.x;
    const int lane = tid & 63, wave = tid >> 6;
    const int quad = lane >> 4, l16 = lane & 15;

    const int a_row = tid >> 2, a_koff = (tid & 3) * 8;
    const float* aP = bias + ((size_t)b * NQ + (s0 + a_row)) * NKV + a_koff;

    const unsigned short* bnP[4];
    const unsigned short* bdP[4];
    int ldsOff[4];
#pragma unroll
    for (int j = 0; j < 4; ++j) {
        int idx = j * 256 + tid;
        int row = idx >> 2, c = idx & 3;
        int kc = c ^ ((row >> 1) & 3);
        bnP[j] = eKVt + ((size_t)b * HD + row) * NKV + kc * 8;
        bdP[j] = eKt  + ((size_t)b * HD + row) * NKV + kc * 8;
        ldsOff[j] = (j * 256 + wave * 64) * 16;
    }

    f32x4 accn[4][4] = {};
    f32x4 accd[4][4] = {};

#pragma unroll
    for (int j = 0; j < 4; ++j) {
        GLL16(bnP[j], (char*)&Bn[0][0] + ldsOff[j]);
        GLL16(bdP[j], (char*)&Bd[0][0] + ldsOff[j]);
    }
    f32x4 c0 = gload4(aP);
    f32x4 c1 = gload4(aP + 4);
    f32x4 n0 = gload4(aP + TK);
    f32x4 n1 = gload4(aP + TK + 4);

    for (int k0 = 0; k0 < NKV; k0 += TK) {
        const int p = (k0 >> 5) & 1, pn = p ^ 1;
        const int kb = (k0 + TK < NKV) ? (k0 + TK) : (NKV - TK);
        const int km = (k0 + 2 * TK < NKV) ? (k0 + 2 * TK) : (NKV - TK);
        char* bnL = (char*)&Bn[pn][0];
        char* bdL = (char*)&Bd[pn][0];
#pragma unroll
        for (int j = 0; j < 4; ++j) {
            GLL16(bnP[j] + kb, bnL + ldsOff[j]);
            GLL16(bdP[j] + kb, bdL + ldsOff[j]);
        }
        asm volatile("s_waitcnt vmcnt(8)" : "+v"(c0), "+v"(c1) :: "memory");
        ushort4 q0, q1;
        q0.x = f2bf(__expf(c0[0])); q0.y = f2bf(__expf(c0[1]));
        q0.z = f2bf(__expf(c0[2])); q0.w = f2bf(__expf(c0[3]));
        q1.x = f2bf(__expf(c1[0])); q1.y = f2bf(__expf(c1[1]));
        q1.z = f2bf(__expf(c1[2])); q1.w = f2bf(__expf(c1[3]));
        *(ushort4*)&As[p][a_row][a_koff]     = q0;
        *(ushort4*)&As[p][a_row][a_koff + 4] = q1;
        f32x4 m0v = gload4(aP + km);
        f32x4 m1v = gload4(aP + km + 4);
        asm volatile("s_waitcnt lgkmcnt(0)\ns_barrier" ::: "memory");
        bf16x8 af[4], bnf[4], bdf[4];
#pragma unroll
        for (int rt = 0; rt < 4; ++rt)
            af[rt] = *(const bf16x8*)&As[p][rt * 16 + l16][quad * 8];
#pragma unroll
        for (int ct = 0; ct < 4; ++ct) {
            int row = wave * 64 + ct * 16 + l16;
            int off = row * 64 + ((quad ^ ((row >> 1) & 3)) * 16);
            bnf[ct] = *(const bf16x8*)((const char*)&Bn[p][0] + off);
            bdf[ct] = *(const bf16x8*)((const char*)&Bd[p][0] + off);
        }
#pragma unroll
        for (int rt = 0; rt < 4; ++rt)
#pragma unroll
            for (int ct = 0; ct < 4; ++ct) {
                accn[rt][ct] = __builtin_amdgcn_mfma_f32_16x16x32_bf16(
                    af[rt], bnf[ct], accn[rt][ct], 0, 0, 0);
                accd[rt][ct] = __builtin_amdgcn_mfma_f32_16x16x32_bf16(
                    af[rt], bdf[ct], accd[rt][ct], 0, 0, 0);
            }
        asm volatile("s_barrier" ::: "memory");
        c0 = n0; c1 = n1; n0 = m0v; n1 = m1v;
    }

#pragma unroll
    for (int rt = 0; rt < 4; ++rt)
#pragma unroll
        for (int ct = 0; ct < 4; ++ct) {
            const int h = wave * 64 + ct * 16 + l16;
#pragma unroll
            for (int r = 0; r < 4; ++r) {
                const int s = s0 + rt * 16 + quad * 4 + r;
                const size_t idx = ((size_t)b * NQ + s) * HD + h;
                Yt[idx] = sigQ[idx] * accn[rt][ct][r] / accd[rt][ct][r];
            }
        }
}

// ---------------------------------------------------------------------------
// Final fp32 GEMM: out = Yt @ f2_w + f2_b   [16384,256]@[256,256]
// ---------------------------------------------------------------------------
#define BM 64
#define BN 64
#define BK 16
#define PADF 4
#define LDAF (BM + PADF)
#define LDBF (BN + PADF)

__global__ __launch_bounds__(256)
void gemm_bias_kernel(const float* __restrict__ X, const float* __restrict__ W,
                      const float* __restrict__ bv, float* __restrict__ out,
                      int M, int N, int K)
{
    __shared__ float As[BK][LDAF];
    __shared__ float Ws[BK][LDBF];
    const int tid = threadIdx.x;
    const int tx = tid & 15, ty = tid >> 4;
    const int row0 = blockIdx.y * BM;
    const int col0 = blockIdx.x * BN;
    const int la_row = tid >> 2, la_col = (tid & 3) * 4;
    const int lw_row = tid >> 4, lw_col = (tid & 15) * 4;

    float acc[4][4] = {};

    const float* Xp = X + (size_t)(row0 + la_row) * K + la_col;
    const float* Wp = W + (size_t)lw_row * N + col0 + lw_col;

    float4 av = *(const float4*)Xp;
    float4 wv = *(const float4*)Wp;

    for (int k0 = 0; k0 < K; k0 += BK) {
        As[la_col + 0][la_row] = av.x;
        As[la_col + 1][la_row] = av.y;
        As[la_col + 2][la_row] = av.z;
        As[la_col + 3][la_row] = av.w;
        *(float4*)&Ws[lw_row][lw_col] = wv;
        __syncthreads();
        if (k0 + BK < K) {
            av = *(const float4*)(Xp + k0 + BK);
            wv = *(const float4*)(Wp + (size_t)(k0 + BK) * N);
        }
#pragma unroll
        for (int kk = 0; kk < BK; ++kk) {
            float4 a4 = *(const float4*)&As[kk][ty * 4];
            float4 w4 = *(const float4*)&Ws[kk][tx * 4];
            float aa[4] = {a4.x, a4.y, a4.z, a4.w};
            float ww[4] = {w4.x, w4.y, w4.z, w4.w};
#pragma unroll
            for (int i = 0; i < 4; ++i)
#pragma unroll
                for (int j = 0; j < 4; ++j)
                    acc[i][j] = fmaf(aa[i], ww[j], acc[i][j]);
        }
        __syncthreads();
    }

    float bb[4];
#pragma unroll
    for (int j = 0; j < 4; ++j) bb[j] = bv[col0 + tx * 4 + j];
#pragma unroll
    for (int i = 0; i < 4; ++i) {
        int r = row0 + ty * 4 + i;
        float4 o;
        o.x = acc[i][0] + bb[0];
        o.y = acc[i][1] + bb[1];
        o.z = acc[i][2] + bb[2];
        o.w = acc[i][3] + bb[3];
        *(float4*)&out[(size_t)r * N + col0 + tx * 4] = o;
    }
}

extern "C" void kernel_launch(void* const* d_in, const int* in_sizes, int n_in,
                              void* d_out, int out_size, void* d_ws, size_t ws_size,
                              hipStream_t stream)
{
    const float* x_q  = (const float*)d_in[0];
    const float* x_kv = (const float*)d_in[1];
    const float* bias = (const float*)d_in[2];
    const float* wq_w = (const float*)d_in[3];
    const float* wq_b = (const float*)d_in[4];
    const float* wk_w = (const float*)d_in[5];
    const float* wk_b = (const float*)d_in[6];
    const float* wv_w = (const float*)d_in[7];
    const float* wv_b = (const float*)d_in[8];
    const float* f2_w = (const float*)d_in[9];
    const float* f2_b = (const float*)d_in[10];
    float* out = (float*)d_out;

    // Workspace: sigQ fp32 | Yt fp32 | eKt bf16 | eKVt bf16 | wqT|wkT|wvT bf16
    float* ws = (float*)d_ws;
    const size_t nBH = (size_t)BATCH * NQ * HD;       // 4,194,304
    float* sigQ = ws;
    float* Yt   = ws + nBH;
    unsigned short* eKt  = (unsigned short*)(ws + 2 * nBH);
    unsigned short* eKVt = eKt + nBH;
    unsigned short* wqT  = eKVt + nBH;
    unsigned short* wkT  = wqT + (size_t)HD * DIN;
    unsigned short* wvT  = wkT + (size_t)HD * DIN;

    const int M = BATCH * NQ;   // 16384
    dim3 blk(256);

    // 0) transpose+convert weights to bf16 [HD][DIN]
    wtrans_kernel<<<dim3(HD / 64, DIN / 64, 3), blk, 0, stream>>>(
        wq_w, wk_w, wv_w, wqT, wkT, wvT);

    // 1) sigQ = sigmoid(x_q @ wq + b)
    proj_q_mfma<<<dim3(M / TS), blk, 0, stream>>>(x_q, wqT, wq_b, sigQ);

    // 2) eKt/eKVt (bf16, transposed) from x_kv
    proj_kv_mfma<<<dim3(M / TS), blk, 0, stream>>>(
        x_kv, wkT, wk_b, wvT, wv_b, eKt, eKVt);

    // 3) Yt = sigQ * (exp(bias)@expKV)/(exp(bias)@expK)
    aft_mfma_kernel<<<dim3(NQ / TS, BATCH), blk, 0, stream>>>(
        bias, eKt, eKVt, sigQ, Yt);

    // 4) out = Yt @ f2_w + f2_b  (fp32, precision guard)
    gemm_bias_kernel<<<dim3(HD / BN, M / BM), blk, 0, stream>>>(
        Yt, f2_w, f2_b, out, M, HD, HD);
}

// Round 3
// 445.013 us; speedup vs baseline: 1.0411x; 1.0264x over previous
//
#include <hip/hip_runtime.h>
#include <cstddef>
#include <cstdint>

// Problem constants
#define BATCH 8
#define NQ    2048
#define NKV   2048
#define DIN   1024
#define HD    256

typedef __attribute__((ext_vector_type(8))) short bf16x8;
typedef __attribute__((ext_vector_type(4))) float f32x4;

__device__ __forceinline__ float sigmoidf_(float x) {
    return 1.0f / (1.0f + expf(-x));
}

// fp32 -> bf16 round-to-nearest-even
__device__ __forceinline__ unsigned short f2bf(float f) {
    union { float f; unsigned int u; } v;
    v.f = f;
    unsigned int u = v.u;
    return (unsigned short)((u + 0x7FFFu + ((u >> 16) & 1u)) >> 16);
}

// async global->LDS, 16 B per lane; lds base must be wave-uniform
#define GLL16(gp, lp)                                                        \
    __builtin_amdgcn_global_load_lds(                                        \
        (const __attribute__((address_space(1))) void*)(gp),                 \
        (__attribute__((address_space(3))) void*)(lp), 16, 0, 0)

// 16B global load via inline asm: keeps vmcnt bookkeeping in OUR hands.
__device__ __forceinline__ f32x4 gload4(const float* p) {
    f32x4 r;
    asm volatile("global_load_dwordx4 %0, %1, off"
                 : "=v"(r) : "v"(p) : "memory");
    return r;
}

// ---------------------------------------------------------------------------
// TILED-SWIZZLED operand layout (the round-3 change):
//   tile(k-step) = [256 rows][32 k] bf16 = 16 KB, stored CONTIGUOUS.
//   Within a row, 8-element chunk c is stored at position kc = c ^ ((row>>1)&3)
//   (same XOR the frag reads already use). Element address:
//     ((kt*256 + row)*32) + (c^((row>>1)&3))*8 + (k&7),  kt = k>>5, c=(k&31)>>3
//   Consumers then stage a k-step with PURE lane-linear GLL (1 KB/wave-inst,
//   the m97-proven fast DMA path) instead of 16 scattered 64B lines per inst.
// ---------------------------------------------------------------------------

// Weight prep: w [DIN][HD] fp32 -> tiled-swizzled bf16 [DIN/32][256][32]
__global__ __launch_bounds__(256)
void wtrans_kernel(const float* __restrict__ w0, const float* __restrict__ w1,
                   const float* __restrict__ w2,
                   unsigned short* __restrict__ t0, unsigned short* __restrict__ t1,
                   unsigned short* __restrict__ t2)
{
    const float* w = (blockIdx.z == 0) ? w0 : (blockIdx.z == 1) ? w1 : w2;
    unsigned short* t = (blockIdx.z == 0) ? t0 : (blockIdx.z == 1) ? t1 : t2;
    const int k0 = blockIdx.y * 64;
    const int n0 = blockIdx.x * 64;
    const int tid = threadIdx.x;
    const int kq = tid >> 4;
    const int nq = tid & 15;
    float4 r[4];
#pragma unroll
    for (int i = 0; i < 4; ++i)
        r[i] = *(const float4*)&w[(size_t)(k0 + kq * 4 + i) * HD + n0 + nq * 4];
    const int k = k0 + kq * 4;          // 4 consecutive k, same 8-chunk
    const int kt = k >> 5;
    const int c  = (k & 31) >> 3;
#pragma unroll
    for (int j = 0; j < 4; ++j) {
        const int h = n0 + nq * 4 + j;
        ushort4 o;
        o.x = f2bf(((const float*)&r[0])[j]);
        o.y = f2bf(((const float*)&r[1])[j]);
        o.z = f2bf(((const float*)&r[2])[j]);
        o.w = f2bf(((const float*)&r[3])[j]);
        const int kc = c ^ ((h >> 1) & 3);
        *(ushort4*)&t[((size_t)kt * 256 + h) * 32 + kc * 8 + (k & 7)] = o;
    }
}

// ---------------------------------------------------------------------------
// Shared tiling: 64(m) x 256(n full) x 32(k). 4 waves; wave w owns the
// 64-wide h-strip [w*64, w*64+64) for all 64 m-rows.  Grid = 256 = 1 blk/CU.
// Pipelined (T3/T4): next B tile GLL'd at TOP of iter into p^1, drained one
// iter later by counted vmcnt; raw s_barrier, never vmcnt(0) in loop.
// ---------------------------------------------------------------------------
#define TS 64
#define TH 256
#define TK 32
#define A_LD 40

// ---------------------------------------------------------------------------
// Q projection: sigQ = sigmoid(x_q @ wq + b)   [16384,1024]@[1024,256]
// ---------------------------------------------------------------------------
__global__ __launch_bounds__(256, 1)
void proj_q_mfma(const float* __restrict__ X,
                 const unsigned short* __restrict__ WT,  // tiled-swizzled
                 const float* __restrict__ bv,
                 float* __restrict__ sigQ)
{
    __shared__ unsigned short As[2][TS][A_LD];
    __shared__ unsigned short Bs[2][TH * TK];

    const int m0 = blockIdx.x * TS;
    const int tid = threadIdx.x;
    const int lane = tid & 63, wave = tid >> 6;
    const int quad = lane >> 4, l16 = lane & 15;

    const int a_row = tid >> 2, a_koff = (tid & 3) * 8;
    const float* aP = X + (size_t)(m0 + a_row) * DIN + a_koff;

    // Lane-linear staging: thread t copies elements (j*256+t)*8..+7 of the
    // 16 KB k-step tile. Per k-step the tile base advances by 256*32 elems.
    const unsigned short* bP[4];
    int ldsOff[4];
#pragma unroll
    for (int j = 0; j < 4; ++j) {
        bP[j] = WT + ((size_t)j * 256 + tid) * 8;
        ldsOff[j] = (j * 256 + wave * 64) * 16;
    }

    f32x4 acc[4][4] = {};

#pragma unroll
    for (int j = 0; j < 4; ++j)
        GLL16(bP[j], (char*)&Bs[0][0] + ldsOff[j]);
    f32x4 c0 = gload4(aP);
    f32x4 c1 = gload4(aP + 4);
    f32x4 n0 = gload4(aP + TK);
    f32x4 n1 = gload4(aP + TK + 4);

    for (int k0 = 0; k0 < DIN; k0 += TK) {
        const int p = (k0 >> 5) & 1, pn = p ^ 1;
        const int kb = (k0 + TK < DIN) ? (k0 + TK) : (DIN - TK);
        const int km = (k0 + 2 * TK < DIN) ? (k0 + 2 * TK) : (DIN - TK);
        char* bL = (char*)&Bs[pn][0];
#pragma unroll
        for (int j = 0; j < 4; ++j)
            GLL16(bP[j] + (size_t)kb * 256, bL + ldsOff[j]);
        asm volatile("s_waitcnt vmcnt(4)" : "+v"(c0), "+v"(c1) :: "memory");
        ushort4 q0, q1;
        q0.x = f2bf(c0[0]); q0.y = f2bf(c0[1]); q0.z = f2bf(c0[2]); q0.w = f2bf(c0[3]);
        q1.x = f2bf(c1[0]); q1.y = f2bf(c1[1]); q1.z = f2bf(c1[2]); q1.w = f2bf(c1[3]);
        *(ushort4*)&As[p][a_row][a_koff]     = q0;
        *(ushort4*)&As[p][a_row][a_koff + 4] = q1;
        f32x4 m0v = gload4(aP + km);
        f32x4 m1v = gload4(aP + km + 4);
        asm volatile("s_waitcnt lgkmcnt(0)\ns_barrier" ::: "memory");
        bf16x8 af[4], bf[4];
#pragma unroll
        for (int rt = 0; rt < 4; ++rt)
            af[rt] = *(const bf16x8*)&As[p][rt * 16 + l16][quad * 8];
#pragma unroll
        for (int ct = 0; ct < 4; ++ct) {
            int row = wave * 64 + ct * 16 + l16;
            int off = row * 64 + ((quad ^ ((row >> 1) & 3)) * 16);
            bf[ct] = *(const bf16x8*)((const char*)&Bs[p][0] + off);
        }
#pragma unroll
        for (int rt = 0; rt < 4; ++rt)
#pragma unroll
            for (int ct = 0; ct < 4; ++ct)
                acc[rt][ct] = __builtin_amdgcn_mfma_f32_16x16x32_bf16(
                    af[rt], bf[ct], acc[rt][ct], 0, 0, 0);
        asm volatile("s_barrier" ::: "memory");
        c0 = n0; c1 = n1; n0 = m0v; n1 = m1v;
    }

#pragma unroll
    for (int rt = 0; rt < 4; ++rt)
#pragma unroll
        for (int ct = 0; ct < 4; ++ct) {
            const int h = wave * 64 + ct * 16 + l16;
            const float bb = bv[h];
#pragma unroll
            for (int r = 0; r < 4; ++r) {
                const int m = m0 + rt * 16 + quad * 4 + r;
                sigQ[(size_t)m * HD + h] = sigmoidf_(acc[rt][ct][r] + bb);
            }
        }
}

// ---------------------------------------------------------------------------
// K/V projection (dual B, shared A): outputs bf16 in TILED-SWIZZLED layout
//   eK/eKV: [b][t/32][256 h][32 t]  (16 KB per (b,t-tile))
// ---------------------------------------------------------------------------
__global__ __launch_bounds__(256, 1)
void proj_kv_mfma(const float* __restrict__ X,
                  const unsigned short* __restrict__ WKT,
                  const float* __restrict__ bk,
                  const unsigned short* __restrict__ WVT,
                  const float* __restrict__ bvv,
                  unsigned short* __restrict__ eKt,
                  unsigned short* __restrict__ eKVt)
{
    __shared__ unsigned short As[2][TS][A_LD];
    __shared__ unsigned short Bk[2][TH * TK];
    __shared__ unsigned short Bv[2][TH * TK];

    const int m0 = blockIdx.x * TS;
    const int tid = threadIdx.x;
    const int lane = tid & 63, wave = tid >> 6;
    const int quad = lane >> 4, l16 = lane & 15;

    const int a_row = tid >> 2, a_koff = (tid & 3) * 8;
    const float* aP = X + (size_t)(m0 + a_row) * DIN + a_koff;

    const unsigned short* bkP[4];
    const unsigned short* bvP[4];
    int ldsOff[4];
#pragma unroll
    for (int j = 0; j < 4; ++j) {
        bkP[j] = WKT + ((size_t)j * 256 + tid) * 8;
        bvP[j] = WVT + ((size_t)j * 256 + tid) * 8;
        ldsOff[j] = (j * 256 + wave * 64) * 16;
    }

    f32x4 acck[4][4] = {};
    f32x4 accv[4][4] = {};

#pragma unroll
    for (int j = 0; j < 4; ++j) {
        GLL16(bkP[j], (char*)&Bk[0][0] + ldsOff[j]);
        GLL16(bvP[j], (char*)&Bv[0][0] + ldsOff[j]);
    }
    f32x4 c0 = gload4(aP);
    f32x4 c1 = gload4(aP + 4);
    f32x4 n0 = gload4(aP + TK);
    f32x4 n1 = gload4(aP + TK + 4);

    for (int k0 = 0; k0 < DIN; k0 += TK) {
        const int p = (k0 >> 5) & 1, pn = p ^ 1;
        const int kb = (k0 + TK < DIN) ? (k0 + TK) : (DIN - TK);
        const int km = (k0 + 2 * TK < DIN) ? (k0 + 2 * TK) : (DIN - TK);
        char* bkL = (char*)&Bk[pn][0];
        char* bvL = (char*)&Bv[pn][0];
#pragma unroll
        for (int j = 0; j < 4; ++j) {
            GLL16(bkP[j] + (size_t)kb * 256, bkL + ldsOff[j]);
            GLL16(bvP[j] + (size_t)kb * 256, bvL + ldsOff[j]);
        }
        asm volatile("s_waitcnt vmcnt(8)" : "+v"(c0), "+v"(c1) :: "memory");
        ushort4 q0, q1;
        q0.x = f2bf(c0[0]); q0.y = f2bf(c0[1]); q0.z = f2bf(c0[2]); q0.w = f2bf(c0[3]);
        q1.x = f2bf(c1[0]); q1.y = f2bf(c1[1]); q1.z = f2bf(c1[2]); q1.w = f2bf(c1[3]);
        *(ushort4*)&As[p][a_row][a_koff]     = q0;
        *(ushort4*)&As[p][a_row][a_koff + 4] = q1;
        f32x4 m0v = gload4(aP + km);
        f32x4 m1v = gload4(aP + km + 4);
        asm volatile("s_waitcnt lgkmcnt(0)\ns_barrier" ::: "memory");
        bf16x8 af[4], bkf[4], bvf[4];
#pragma unroll
        for (int rt = 0; rt < 4; ++rt)
            af[rt] = *(const bf16x8*)&As[p][rt * 16 + l16][quad * 8];
#pragma unroll
        for (int ct = 0; ct < 4; ++ct) {
            int row = wave * 64 + ct * 16 + l16;
            int off = row * 64 + ((quad ^ ((row >> 1) & 3)) * 16);
            bkf[ct] = *(const bf16x8*)((const char*)&Bk[p][0] + off);
            bvf[ct] = *(const bf16x8*)((const char*)&Bv[p][0] + off);
        }
#pragma unroll
        for (int rt = 0; rt < 4; ++rt)
#pragma unroll
            for (int ct = 0; ct < 4; ++ct) {
                acck[rt][ct] = __builtin_amdgcn_mfma_f32_16x16x32_bf16(
                    af[rt], bkf[ct], acck[rt][ct], 0, 0, 0);
                accv[rt][ct] = __builtin_amdgcn_mfma_f32_16x16x32_bf16(
                    af[rt], bvf[ct], accv[rt][ct], 0, 0, 0);
            }
        asm volatile("s_barrier" ::: "memory");
        c0 = n0; c1 = n1; n0 = m0v; n1 = m1v;
    }

    const int bidx = m0 >> 11;
    const int tb = m0 & (NKV - 1);
#pragma unroll
    for (int rt = 0; rt < 4; ++rt)
#pragma unroll
        for (int ct = 0; ct < 4; ++ct) {
            const int h = wave * 64 + ct * 16 + l16;
            const float bkb = bk[h];
            const float bvb = bvv[h];
            ushort4 pk, pv;
            unsigned short* pK = (unsigned short*)&pk;
            unsigned short* pV = (unsigned short*)&pv;
#pragma unroll
            for (int r = 0; r < 4; ++r) {
                float e  = __expf(acck[rt][ct][r] + bkb);
                float ev = e * (accv[rt][ct][r] + bvb);
                pK[r] = f2bf(e);
                pV[r] = f2bf(ev);
            }
            const int t0a = tb + rt * 16 + quad * 4;      // 4 consecutive t
            const int tt = t0a >> 5, tc = t0a & 31;
            const int kc = (tc >> 3) ^ ((h >> 1) & 3);
            size_t idx = (((size_t)bidx * (NKV / 32) + tt) * 256 + h) * 32
                         + kc * 8 + (tc & 7);
            *(ushort4*)&eKt[idx]  = pk;
            *(ushort4*)&eKVt[idx] = pv;
        }
}

// ---------------------------------------------------------------------------
// Core AFT einsum: full-H tile, exp(bias) staged once, dual B via gll.
//   Yt[s,h] = sigQ * (exp(bias)@expKV) / (exp(bias)@expK)
// batch = lin & 7 (XCD-affine: each XCD's L2 keeps one batch's 2 MB of eK/eKV)
// B-staging is now a contiguous 16 KB tile copy per array per k-step.
// ---------------------------------------------------------------------------
__global__ __launch_bounds__(256, 1)
void aft_mfma_kernel(const float* __restrict__ bias,
                     const unsigned short* __restrict__ eKt,    // tiled-swz
                     const unsigned short* __restrict__ eKVt,   // tiled-swz
                     const float* __restrict__ sigQ,
                     float* __restrict__ Yt)
{
    __shared__ unsigned short As[2][TS][A_LD];
    __shared__ unsigned short Bn[2][TH * TK];
    __shared__ unsigned short Bd[2][TH * TK];

    const int lin = blockIdx.y * gridDim.x + blockIdx.x;  // 0..255
    const int b   = lin & 7;                              // batch == XCD id
    const int s0  = (lin >> 3) * TS;
    const int tid = threadIdx.x;
    const int lane = tid & 63, wave = tid >> 6;
    const int quad = lane >> 4, l16 = lane & 15;

    const int a_row = tid >> 2, a_koff = (tid & 3) * 8;
    const float* aP = bias + ((size_t)b * NQ + (s0 + a_row)) * NKV + a_koff;

    const unsigned short* bnP[4];
    const unsigned short* bdP[4];
    int ldsOff[4];
#pragma unroll
    for (int j = 0; j < 4; ++j) {
        const size_t base = (size_t)b * (NKV / 32) * 256 * 32;
        bnP[j] = eKVt + base + ((size_t)j * 256 + tid) * 8;
        bdP[j] = eKt  + base + ((size_t)j * 256 + tid) * 8;
        ldsOff[j] = (j * 256 + wave * 64) * 16;
    }

    f32x4 accn[4][4] = {};
    f32x4 accd[4][4] = {};

#pragma unroll
    for (int j = 0; j < 4; ++j) {
        GLL16(bnP[j], (char*)&Bn[0][0] + ldsOff[j]);
        GLL16(bdP[j], (char*)&Bd[0][0] + ldsOff[j]);
    }
    f32x4 c0 = gload4(aP);
    f32x4 c1 = gload4(aP + 4);
    f32x4 n0 = gload4(aP + TK);
    f32x4 n1 = gload4(aP + TK + 4);

    for (int k0 = 0; k0 < NKV; k0 += TK) {
        const int p = (k0 >> 5) & 1, pn = p ^ 1;
        const int kb = (k0 + TK < NKV) ? (k0 + TK) : (NKV - TK);
        const int km = (k0 + 2 * TK < NKV) ? (k0 + 2 * TK) : (NKV - TK);
        char* bnL = (char*)&Bn[pn][0];
        char* bdL = (char*)&Bd[pn][0];
#pragma unroll
        for (int j = 0; j < 4; ++j) {
            GLL16(bnP[j] + (size_t)kb * 256, bnL + ldsOff[j]);
            GLL16(bdP[j] + (size_t)kb * 256, bdL + ldsOff[j]);
        }
        asm volatile("s_waitcnt vmcnt(8)" : "+v"(c0), "+v"(c1) :: "memory");
        ushort4 q0, q1;
        q0.x = f2bf(__expf(c0[0])); q0.y = f2bf(__expf(c0[1]));
        q0.z = f2bf(__expf(c0[2])); q0.w = f2bf(__expf(c0[3]));
        q1.x = f2bf(__expf(c1[0])); q1.y = f2bf(__expf(c1[1]));
        q1.z = f2bf(__expf(c1[2])); q1.w = f2bf(__expf(c1[3]));
        *(ushort4*)&As[p][a_row][a_koff]     = q0;
        *(ushort4*)&As[p][a_row][a_koff + 4] = q1;
        f32x4 m0v = gload4(aP + km);
        f32x4 m1v = gload4(aP + km + 4);
        asm volatile("s_waitcnt lgkmcnt(0)\ns_barrier" ::: "memory");
        bf16x8 af[4], bnf[4], bdf[4];
#pragma unroll
        for (int rt = 0; rt < 4; ++rt)
            af[rt] = *(const bf16x8*)&As[p][rt * 16 + l16][quad * 8];
#pragma unroll
        for (int ct = 0; ct < 4; ++ct) {
            int row = wave * 64 + ct * 16 + l16;
            int off = row * 64 + ((quad ^ ((row >> 1) & 3)) * 16);
            bnf[ct] = *(const bf16x8*)((const char*)&Bn[p][0] + off);
            bdf[ct] = *(const bf16x8*)((const char*)&Bd[p][0] + off);
        }
#pragma unroll
        for (int rt = 0; rt < 4; ++rt)
#pragma unroll
            for (int ct = 0; ct < 4; ++ct) {
                accn[rt][ct] = __builtin_amdgcn_mfma_f32_16x16x32_bf16(
                    af[rt], bnf[ct], accn[rt][ct], 0, 0, 0);
                accd[rt][ct] = __builtin_amdgcn_mfma_f32_16x16x32_bf16(
                    af[rt], bdf[ct], accd[rt][ct], 0, 0, 0);
            }
        asm volatile("s_barrier" ::: "memory");
        c0 = n0; c1 = n1; n0 = m0v; n1 = m1v;
    }

#pragma unroll
    for (int rt = 0; rt < 4; ++rt)
#pragma unroll
        for (int ct = 0; ct < 4; ++ct) {
            const int h = wave * 64 + ct * 16 + l16;
#pragma unroll
            for (int r = 0; r < 4; ++r) {
                const int s = s0 + rt * 16 + quad * 4 + r;
                const size_t idx = ((size_t)b * NQ + s) * HD + h;
                Yt[idx] = sigQ[idx] * accn[rt][ct][r] / accd[rt][ct][r];
            }
        }
}

// ---------------------------------------------------------------------------
// Final fp32 GEMM: out = Yt @ f2_w + f2_b   [16384,256]@[256,256]
// ---------------------------------------------------------------------------
#define BM 64
#define BN 64
#define BK 16
#define PADF 4
#define LDAF (BM + PADF)
#define LDBF (BN + PADF)

__global__ __launch_bounds__(256)
void gemm_bias_kernel(const float* __restrict__ X, const float* __restrict__ W,
                      const float* __restrict__ bv, float* __restrict__ out,
                      int M, int N, int K)
{
    __shared__ float As[BK][LDAF];
    __shared__ float Ws[BK][LDBF];
    const int tid = threadIdx.x;
    const int tx = tid & 15, ty = tid >> 4;
    const int row0 = blockIdx.y * BM;
    const int col0 = blockIdx.x * BN;
    const int la_row = tid >> 2, la_col = (tid & 3) * 4;
    const int lw_row = tid >> 4, lw_col = (tid & 15) * 4;

    float acc[4][4] = {};

    const float* Xp = X + (size_t)(row0 + la_row) * K + la_col;
    const float* Wp = W + (size_t)lw_row * N + col0 + lw_col;

    float4 av = *(const float4*)Xp;
    float4 wv = *(const float4*)Wp;

    for (int k0 = 0; k0 < K; k0 += BK) {
        As[la_col + 0][la_row] = av.x;
        As[la_col + 1][la_row] = av.y;
        As[la_col + 2][la_row] = av.z;
        As[la_col + 3][la_row] = av.w;
        *(float4*)&Ws[lw_row][lw_col] = wv;
        __syncthreads();
        if (k0 + BK < K) {
            av = *(const float4*)(Xp + k0 + BK);
            wv = *(const float4*)(Wp + (size_t)(k0 + BK) * N);
        }
#pragma unroll
        for (int kk = 0; kk < BK; ++kk) {
            float4 a4 = *(const float4*)&As[kk][ty * 4];
            float4 w4 = *(const float4*)&Ws[kk][tx * 4];
            float aa[4] = {a4.x, a4.y, a4.z, a4.w};
            float ww[4] = {w4.x, w4.y, w4.z, w4.w};
#pragma unroll
            for (int i = 0; i < 4; ++i)
#pragma unroll
                for (int j = 0; j < 4; ++j)
                    acc[i][j] = fmaf(aa[i], ww[j], acc[i][j]);
        }
        __syncthreads();
    }

    float bb[4];
#pragma unroll
    for (int j = 0; j < 4; ++j) bb[j] = bv[col0 + tx * 4 + j];
#pragma unroll
    for (int i = 0; i < 4; ++i) {
        int r = row0 + ty * 4 + i;
        float4 o;
        o.x = acc[i][0] + bb[0];
        o.y = acc[i][1] + bb[1];
        o.z = acc[i][2] + bb[2];
        o.w = acc[i][3] + bb[3];
        *(float4*)&out[(size_t)r * N + col0 + tx * 4] = o;
    }
}

extern "C" void kernel_launch(void* const* d_in, const int* in_sizes, int n_in,
                              void* d_out, int out_size, void* d_ws, size_t ws_size,
                              hipStream_t stream)
{
    const float* x_q  = (const float*)d_in[0];
    const float* x_kv = (const float*)d_in[1];
    const float* bias = (const float*)d_in[2];
    const float* wq_w = (const float*)d_in[3];
    const float* wq_b = (const float*)d_in[4];
    const float* wk_w = (const float*)d_in[5];
    const float* wk_b = (const float*)d_in[6];
    const float* wv_w = (const float*)d_in[7];
    const float* wv_b = (const float*)d_in[8];
    const float* f2_w = (const float*)d_in[9];
    const float* f2_b = (const float*)d_in[10];
    float* out = (float*)d_out;

    // Workspace: sigQ fp32 | Yt fp32 | eKt bf16 | eKVt bf16 | wqT|wkT|wvT bf16
    float* ws = (float*)d_ws;
    const size_t nBH = (size_t)BATCH * NQ * HD;       // 4,194,304
    float* sigQ = ws;
    float* Yt   = ws + nBH;
    unsigned short* eKt  = (unsigned short*)(ws + 2 * nBH);
    unsigned short* eKVt = eKt + nBH;
    unsigned short* wqT  = eKVt + nBH;
    unsigned short* wkT  = wqT + (size_t)HD * DIN;
    unsigned short* wvT  = wkT + (size_t)HD * DIN;

    const int M = BATCH * NQ;   // 16384
    dim3 blk(256);

    // 0) weights -> tiled-swizzled bf16
    wtrans_kernel<<<dim3(HD / 64, DIN / 64, 3), blk, 0, stream>>>(
        wq_w, wk_w, wv_w, wqT, wkT, wvT);

    // 1) sigQ = sigmoid(x_q @ wq + b)
    proj_q_mfma<<<dim3(M / TS), blk, 0, stream>>>(x_q, wqT, wq_b, sigQ);

    // 2) eKt/eKVt (bf16, tiled-swizzled) from x_kv
    proj_kv_mfma<<<dim3(M / TS), blk, 0, stream>>>(
        x_kv, wkT, wk_b, wvT, wv_b, eKt, eKVt);

    // 3) Yt = sigQ * (exp(bias)@expKV)/(exp(bias)@expK)
    aft_mfma_kernel<<<dim3(NQ / TS, BATCH), blk, 0, stream>>>(
        bias, eKt, eKVt, sigQ, Yt);

    // 4) out = Yt @ f2_w + f2_b  (fp32, precision guard)
    gemm_bias_kernel<<<dim3(HD / BN, M / BM), blk, 0, stream>>>(
        Yt, f2_w, f2_b, out, M, HD, HD);
}

// Round 4
// 441.913 us; speedup vs baseline: 1.0484x; 1.0070x over previous
//
#include <hip/hip_runtime.h>
#include <cstddef>
#include <cstdint>

// Problem constants
#define BATCH 8
#define NQ    2048
#define NKV   2048
#define DIN   1024
#define HD    256

typedef __attribute__((ext_vector_type(8))) short bf16x8;
typedef __attribute__((ext_vector_type(4))) float f32x4;

__device__ __forceinline__ float sigmoidf_(float x) {
    return 1.0f / (1.0f + expf(-x));
}

// fp32 -> bf16 round-to-nearest-even
__device__ __forceinline__ unsigned short f2bf(float f) {
    union { float f; unsigned int u; } v;
    v.f = f;
    unsigned int u = v.u;
    return (unsigned short)((u + 0x7FFFu + ((u >> 16) & 1u)) >> 16);
}

// async global->LDS, 16 B per lane; lds base must be wave-uniform
#define GLL16(gp, lp)                                                        \
    __builtin_amdgcn_global_load_lds(                                        \
        (const __attribute__((address_space(1))) void*)(gp),                 \
        (__attribute__((address_space(3))) void*)(lp), 16, 0, 0)

// ---------------------------------------------------------------------------
// TILED-SWIZZLED operand layout:
//   tile(k-step) = [256 rows][32 k] bf16 = 16 KB, stored CONTIGUOUS.
//   Within a row, 8-elem chunk c sits at kc = c ^ ((row>>1)&3) (the XOR the
//   frag reads use). Consumers stage a k-step with pure lane-linear GLL.
// ---------------------------------------------------------------------------

// Weight prep: w [DIN][HD] fp32 -> tiled-swizzled bf16 [DIN/32][256][32]
__global__ __launch_bounds__(256)
void wtrans_kernel(const float* __restrict__ w0, const float* __restrict__ w1,
                   const float* __restrict__ w2,
                   unsigned short* __restrict__ t0, unsigned short* __restrict__ t1,
                   unsigned short* __restrict__ t2)
{
    const float* w = (blockIdx.z == 0) ? w0 : (blockIdx.z == 1) ? w1 : w2;
    unsigned short* t = (blockIdx.z == 0) ? t0 : (blockIdx.z == 1) ? t1 : t2;
    const int k0 = blockIdx.y * 64;
    const int n0 = blockIdx.x * 64;
    const int tid = threadIdx.x;
    const int kq = tid >> 4;
    const int nq = tid & 15;
    float4 r[4];
#pragma unroll
    for (int i = 0; i < 4; ++i)
        r[i] = *(const float4*)&w[(size_t)(k0 + kq * 4 + i) * HD + n0 + nq * 4];
    const int k = k0 + kq * 4;          // 4 consecutive k, same 8-chunk
    const int kt = k >> 5;
    const int c  = (k & 31) >> 3;
#pragma unroll
    for (int j = 0; j < 4; ++j) {
        const int h = n0 + nq * 4 + j;
        ushort4 o;
        o.x = f2bf(((const float*)&r[0])[j]);
        o.y = f2bf(((const float*)&r[1])[j]);
        o.z = f2bf(((const float*)&r[2])[j]);
        o.w = f2bf(((const float*)&r[3])[j]);
        const int kc = c ^ ((h >> 1) & 3);
        *(ushort4*)&t[((size_t)kt * 256 + h) * 32 + kc * 8 + (k & 7)] = o;
    }
}

// ---------------------------------------------------------------------------
// Shared tiling: 64(m) x 256(n full) x 32(k). 4 waves; wave w owns the
// 64-wide h-strip [w*64, w*64+64).
// Round-4 structure: SINGLE-buffered LDS (minimal footprint) + plain
// __syncthreads drain loop (R0's schedule, measured fastest) + 2-3 blocks/CU
// co-residency so DMA latency in one block hides under compute in another
// (the m114 inter-block overlap mechanism). Single-buffering is safe in the
// 2-sync loop: writes of iter k+1 happen after the sync ending reads of k.
// ---------------------------------------------------------------------------
#define TS 64
#define TH 256
#define TK 32
#define A_LD 40

// ---------------------------------------------------------------------------
// Q projection: sigQ = sigmoid(x_q @ wq + b)   [16384,1024]@[1024,256]
// LDS 21.5 KB, launch_bounds(256,3) -> 3 blocks/CU (12 waves).
// ---------------------------------------------------------------------------
__global__ __launch_bounds__(256, 3)
void proj_q_mfma(const float* __restrict__ X,
                 const unsigned short* __restrict__ WT,  // tiled-swizzled
                 const float* __restrict__ bv,
                 float* __restrict__ sigQ)
{
    __shared__ unsigned short As[TS][A_LD];
    __shared__ unsigned short Bs[TH * TK];

    const int m0 = blockIdx.x * TS;
    const int tid = threadIdx.x;
    const int lane = tid & 63, wave = tid >> 6;
    const int quad = lane >> 4, l16 = lane & 15;

    const int a_row = tid >> 2, a_koff = (tid & 3) * 8;
    const float* aP = X + (size_t)(m0 + a_row) * DIN + a_koff;

    const unsigned short* bP[4];
    int ldsOff[4];
#pragma unroll
    for (int j = 0; j < 4; ++j) {
        bP[j] = WT + ((size_t)j * 256 + tid) * 8;
        ldsOff[j] = (j * 256 + wave * 64) * 16;
    }

    f32x4 acc[4][4] = {};
    float4 a0 = *(const float4*)aP;
    float4 a1 = *(const float4*)(aP + 4);

    for (int k0 = 0; k0 < DIN; k0 += TK) {
        ushort4 q0, q1;
        q0.x = f2bf(a0.x); q0.y = f2bf(a0.y); q0.z = f2bf(a0.z); q0.w = f2bf(a0.w);
        q1.x = f2bf(a1.x); q1.y = f2bf(a1.y); q1.z = f2bf(a1.z); q1.w = f2bf(a1.w);
        *(ushort4*)&As[a_row][a_koff]     = q0;
        *(ushort4*)&As[a_row][a_koff + 4] = q1;
        char* bL = (char*)&Bs[0];
#pragma unroll
        for (int j = 0; j < 4; ++j)
            GLL16(bP[j] + (size_t)k0 * 256, bL + ldsOff[j]);
        __syncthreads();
        if (k0 + TK < DIN) {
            a0 = *(const float4*)(aP + k0 + TK);
            a1 = *(const float4*)(aP + k0 + TK + 4);
        }
        bf16x8 af[4], bf[4];
#pragma unroll
        for (int rt = 0; rt < 4; ++rt)
            af[rt] = *(const bf16x8*)&As[rt * 16 + l16][quad * 8];
#pragma unroll
        for (int ct = 0; ct < 4; ++ct) {
            int row = wave * 64 + ct * 16 + l16;
            int off = row * 64 + ((quad ^ ((row >> 1) & 3)) * 16);
            bf[ct] = *(const bf16x8*)((const char*)&Bs[0] + off);
        }
#pragma unroll
        for (int rt = 0; rt < 4; ++rt)
#pragma unroll
            for (int ct = 0; ct < 4; ++ct)
                acc[rt][ct] = __builtin_amdgcn_mfma_f32_16x16x32_bf16(
                    af[rt], bf[ct], acc[rt][ct], 0, 0, 0);
        __syncthreads();
    }

#pragma unroll
    for (int rt = 0; rt < 4; ++rt)
#pragma unroll
        for (int ct = 0; ct < 4; ++ct) {
            const int h = wave * 64 + ct * 16 + l16;
            const float bb = bv[h];
#pragma unroll
            for (int r = 0; r < 4; ++r) {
                const int m = m0 + rt * 16 + quad * 4 + r;
                sigQ[(size_t)m * HD + h] = sigmoidf_(acc[rt][ct][r] + bb);
            }
        }
}

// ---------------------------------------------------------------------------
// K/V projection (dual B, shared A): outputs bf16 in TILED-SWIZZLED layout
//   eK/eKV: [b][t/32][256 h][32 t]  (16 KB per (b,t-tile))
// LDS 37.9 KB, launch_bounds(256,2) -> 2 blocks/CU.
// ---------------------------------------------------------------------------
__global__ __launch_bounds__(256, 2)
void proj_kv_mfma(const float* __restrict__ X,
                  const unsigned short* __restrict__ WKT,
                  const float* __restrict__ bk,
                  const unsigned short* __restrict__ WVT,
                  const float* __restrict__ bvv,
                  unsigned short* __restrict__ eKt,
                  unsigned short* __restrict__ eKVt)
{
    __shared__ unsigned short As[TS][A_LD];
    __shared__ unsigned short Bk[TH * TK];
    __shared__ unsigned short Bv[TH * TK];

    const int m0 = blockIdx.x * TS;
    const int tid = threadIdx.x;
    const int lane = tid & 63, wave = tid >> 6;
    const int quad = lane >> 4, l16 = lane & 15;

    const int a_row = tid >> 2, a_koff = (tid & 3) * 8;
    const float* aP = X + (size_t)(m0 + a_row) * DIN + a_koff;

    const unsigned short* bkP[4];
    const unsigned short* bvP[4];
    int ldsOff[4];
#pragma unroll
    for (int j = 0; j < 4; ++j) {
        bkP[j] = WKT + ((size_t)j * 256 + tid) * 8;
        bvP[j] = WVT + ((size_t)j * 256 + tid) * 8;
        ldsOff[j] = (j * 256 + wave * 64) * 16;
    }

    f32x4 acck[4][4] = {};
    f32x4 accv[4][4] = {};
    float4 a0 = *(const float4*)aP;
    float4 a1 = *(const float4*)(aP + 4);

    for (int k0 = 0; k0 < DIN; k0 += TK) {
        ushort4 q0, q1;
        q0.x = f2bf(a0.x); q0.y = f2bf(a0.y); q0.z = f2bf(a0.z); q0.w = f2bf(a0.w);
        q1.x = f2bf(a1.x); q1.y = f2bf(a1.y); q1.z = f2bf(a1.z); q1.w = f2bf(a1.w);
        *(ushort4*)&As[a_row][a_koff]     = q0;
        *(ushort4*)&As[a_row][a_koff + 4] = q1;
        char* bkL = (char*)&Bk[0];
        char* bvL = (char*)&Bv[0];
#pragma unroll
        for (int j = 0; j < 4; ++j) {
            GLL16(bkP[j] + (size_t)k0 * 256, bkL + ldsOff[j]);
            GLL16(bvP[j] + (size_t)k0 * 256, bvL + ldsOff[j]);
        }
        __syncthreads();
        if (k0 + TK < DIN) {
            a0 = *(const float4*)(aP + k0 + TK);
            a1 = *(const float4*)(aP + k0 + TK + 4);
        }
        bf16x8 af[4], bkf[4], bvf[4];
#pragma unroll
        for (int rt = 0; rt < 4; ++rt)
            af[rt] = *(const bf16x8*)&As[rt * 16 + l16][quad * 8];
#pragma unroll
        for (int ct = 0; ct < 4; ++ct) {
            int row = wave * 64 + ct * 16 + l16;
            int off = row * 64 + ((quad ^ ((row >> 1) & 3)) * 16);
            bkf[ct] = *(const bf16x8*)((const char*)&Bk[0] + off);
            bvf[ct] = *(const bf16x8*)((const char*)&Bv[0] + off);
        }
#pragma unroll
        for (int rt = 0; rt < 4; ++rt)
#pragma unroll
            for (int ct = 0; ct < 4; ++ct) {
                acck[rt][ct] = __builtin_amdgcn_mfma_f32_16x16x32_bf16(
                    af[rt], bkf[ct], acck[rt][ct], 0, 0, 0);
                accv[rt][ct] = __builtin_amdgcn_mfma_f32_16x16x32_bf16(
                    af[rt], bvf[ct], accv[rt][ct], 0, 0, 0);
            }
        __syncthreads();
    }

    const int bidx = m0 >> 11;
    const int tb = m0 & (NKV - 1);
#pragma unroll
    for (int rt = 0; rt < 4; ++rt)
#pragma unroll
        for (int ct = 0; ct < 4; ++ct) {
            const int h = wave * 64 + ct * 16 + l16;
            const float bkb = bk[h];
            const float bvb = bvv[h];
            ushort4 pk, pv;
            unsigned short* pK = (unsigned short*)&pk;
            unsigned short* pV = (unsigned short*)&pv;
#pragma unroll
            for (int r = 0; r < 4; ++r) {
                float e  = __expf(acck[rt][ct][r] + bkb);
                float ev = e * (accv[rt][ct][r] + bvb);
                pK[r] = f2bf(e);
                pV[r] = f2bf(ev);
            }
            const int t0a = tb + rt * 16 + quad * 4;      // 4 consecutive t
            const int tt = t0a >> 5, tc = t0a & 31;
            const int kc = (tc >> 3) ^ ((h >> 1) & 3);
            size_t idx = (((size_t)bidx * (NKV / 32) + tt) * 256 + h) * 32
                         + kc * 8 + (tc & 7);
            *(ushort4*)&eKt[idx]  = pk;
            *(ushort4*)&eKVt[idx] = pv;
        }
}

// ---------------------------------------------------------------------------
// Core AFT einsum: full-H tile, exp(bias) staged once, dual B via gll.
//   Yt[s,h] = sigQ * (exp(bias)@expKV) / (exp(bias)@expK)
// batch = lin & 7 (XCD-affine L2 residency for eK/eKV).
// LDS 37.9 KB, launch_bounds(256,2) -> 2 blocks/CU.
// ---------------------------------------------------------------------------
__global__ __launch_bounds__(256, 2)
void aft_mfma_kernel(const float* __restrict__ bias,
                     const unsigned short* __restrict__ eKt,    // tiled-swz
                     const unsigned short* __restrict__ eKVt,   // tiled-swz
                     const float* __restrict__ sigQ,
                     float* __restrict__ Yt)
{
    __shared__ unsigned short As[TS][A_LD];
    __shared__ unsigned short Bn[TH * TK];
    __shared__ unsigned short Bd[TH * TK];

    const int lin = blockIdx.y * gridDim.x + blockIdx.x;  // 0..255
    const int b   = lin & 7;                              // batch == XCD id
    const int s0  = (lin >> 3) * TS;
    const int tid = threadIdx.x;
    const int lane = tid & 63, wave = tid >> 6;
    const int quad = lane >> 4, l16 = lane & 15;

    const int a_row = tid >> 2, a_koff = (tid & 3) * 8;
    const float* aP = bias + ((size_t)b * NQ + (s0 + a_row)) * NKV + a_koff;

    const unsigned short* bnP[4];
    const unsigned short* bdP[4];
    int ldsOff[4];
#pragma unroll
    for (int j = 0; j < 4; ++j) {
        const size_t base = (size_t)b * (NKV / 32) * 256 * 32;
        bnP[j] = eKVt + base + ((size_t)j * 256 + tid) * 8;
        bdP[j] = eKt  + base + ((size_t)j * 256 + tid) * 8;
        ldsOff[j] = (j * 256 + wave * 64) * 16;
    }

    f32x4 accn[4][4] = {};
    f32x4 accd[4][4] = {};
    float4 a0 = *(const float4*)aP;
    float4 a1 = *(const float4*)(aP + 4);

    for (int k0 = 0; k0 < NKV; k0 += TK) {
        ushort4 q0, q1;
        q0.x = f2bf(__expf(a0.x)); q0.y = f2bf(__expf(a0.y));
        q0.z = f2bf(__expf(a0.z)); q0.w = f2bf(__expf(a0.w));
        q1.x = f2bf(__expf(a1.x)); q1.y = f2bf(__expf(a1.y));
        q1.z = f2bf(__expf(a1.z)); q1.w = f2bf(__expf(a1.w));
        *(ushort4*)&As[a_row][a_koff]     = q0;
        *(ushort4*)&As[a_row][a_koff + 4] = q1;
        char* bnL = (char*)&Bn[0];
        char* bdL = (char*)&Bd[0];
#pragma unroll
        for (int j = 0; j < 4; ++j) {
            GLL16(bnP[j] + (size_t)k0 * 256, bnL + ldsOff[j]);
            GLL16(bdP[j] + (size_t)k0 * 256, bdL + ldsOff[j]);
        }
        __syncthreads();
        if (k0 + TK < NKV) {
            a0 = *(const float4*)(aP + k0 + TK);
            a1 = *(const float4*)(aP + k0 + TK + 4);
        }
        bf16x8 af[4], bnf[4], bdf[4];
#pragma unroll
        for (int rt = 0; rt < 4; ++rt)
            af[rt] = *(const bf16x8*)&As[rt * 16 + l16][quad * 8];
#pragma unroll
        for (int ct = 0; ct < 4; ++ct) {
            int row = wave * 64 + ct * 16 + l16;
            int off = row * 64 + ((quad ^ ((row >> 1) & 3)) * 16);
            bnf[ct] = *(const bf16x8*)((const char*)&Bn[0] + off);
            bdf[ct] = *(const bf16x8*)((const char*)&Bd[0] + off);
        }
#pragma unroll
        for (int rt = 0; rt < 4; ++rt)
#pragma unroll
            for (int ct = 0; ct < 4; ++ct) {
                accn[rt][ct] = __builtin_amdgcn_mfma_f32_16x16x32_bf16(
                    af[rt], bnf[ct], accn[rt][ct], 0, 0, 0);
                accd[rt][ct] = __builtin_amdgcn_mfma_f32_16x16x32_bf16(
                    af[rt], bdf[ct], accd[rt][ct], 0, 0, 0);
            }
        __syncthreads();
    }

#pragma unroll
    for (int rt = 0; rt < 4; ++rt)
#pragma unroll
        for (int ct = 0; ct < 4; ++ct) {
            const int h = wave * 64 + ct * 16 + l16;
#pragma unroll
            for (int r = 0; r < 4; ++r) {
                const int s = s0 + rt * 16 + quad * 4 + r;
                const size_t idx = ((size_t)b * NQ + s) * HD + h;
                Yt[idx] = sigQ[idx] * accn[rt][ct][r] / accd[rt][ct][r];
            }
        }
}

// ---------------------------------------------------------------------------
// Final fp32 GEMM: out = Yt @ f2_w + f2_b   [16384,256]@[256,256]
// ---------------------------------------------------------------------------
#define BM 64
#define BN 64
#define BK 16
#define PADF 4
#define LDAF (BM + PADF)
#define LDBF (BN + PADF)

__global__ __launch_bounds__(256)
void gemm_bias_kernel(const float* __restrict__ X, const float* __restrict__ W,
                      const float* __restrict__ bv, float* __restrict__ out,
                      int M, int N, int K)
{
    __shared__ float As[BK][LDAF];
    __shared__ float Ws[BK][LDBF];
    const int tid = threadIdx.x;
    const int tx = tid & 15, ty = tid >> 4;
    const int row0 = blockIdx.y * BM;
    const int col0 = blockIdx.x * BN;
    const int la_row = tid >> 2, la_col = (tid & 3) * 4;
    const int lw_row = tid >> 4, lw_col = (tid & 15) * 4;

    float acc[4][4] = {};

    const float* Xp = X + (size_t)(row0 + la_row) * K + la_col;
    const float* Wp = W + (size_t)lw_row * N + col0 + lw_col;

    float4 av = *(const float4*)Xp;
    float4 wv = *(const float4*)Wp;

    for (int k0 = 0; k0 < K; k0 += BK) {
        As[la_col + 0][la_row] = av.x;
        As[la_col + 1][la_row] = av.y;
        As[la_col + 2][la_row] = av.z;
        As[la_col + 3][la_row] = av.w;
        *(float4*)&Ws[lw_row][lw_col] = wv;
        __syncthreads();
        if (k0 + BK < K) {
            av = *(const float4*)(Xp + k0 + BK);
            wv = *(const float4*)(Wp + (size_t)(k0 + BK) * N);
        }
#pragma unroll
        for (int kk = 0; kk < BK; ++kk) {
            float4 a4 = *(const float4*)&As[kk][ty * 4];
            float4 w4 = *(const float4*)&Ws[kk][tx * 4];
            float aa[4] = {a4.x, a4.y, a4.z, a4.w};
            float ww[4] = {w4.x, w4.y, w4.z, w4.w};
#pragma unroll
            for (int i = 0; i < 4; ++i)
#pragma unroll
                for (int j = 0; j < 4; ++j)
                    acc[i][j] = fmaf(aa[i], ww[j], acc[i][j]);
        }
        __syncthreads();
    }

    float bb[4];
#pragma unroll
    for (int j = 0; j < 4; ++j) bb[j] = bv[col0 + tx * 4 + j];
#pragma unroll
    for (int i = 0; i < 4; ++i) {
        int r = row0 + ty * 4 + i;
        float4 o;
        o.x = acc[i][0] + bb[0];
        o.y = acc[i][1] + bb[1];
        o.z = acc[i][2] + bb[2];
        o.w = acc[i][3] + bb[3];
        *(float4*)&out[(size_t)r * N + col0 + tx * 4] = o;
    }
}

extern "C" void kernel_launch(void* const* d_in, const int* in_sizes, int n_in,
                              void* d_out, int out_size, void* d_ws, size_t ws_size,
                              hipStream_t stream)
{
    const float* x_q  = (const float*)d_in[0];
    const float* x_kv = (const float*)d_in[1];
    const float* bias = (const float*)d_in[2];
    const float* wq_w = (const float*)d_in[3];
    const float* wq_b = (const float*)d_in[4];
    const float* wk_w = (const float*)d_in[5];
    const float* wk_b = (const float*)d_in[6];
    const float* wv_w = (const float*)d_in[7];
    const float* wv_b = (const float*)d_in[8];
    const float* f2_w = (const float*)d_in[9];
    const float* f2_b = (const float*)d_in[10];
    float* out = (float*)d_out;

    // Workspace: sigQ fp32 | Yt fp32 | eKt bf16 | eKVt bf16 | wqT|wkT|wvT bf16
    float* ws = (float*)d_ws;
    const size_t nBH = (size_t)BATCH * NQ * HD;       // 4,194,304
    float* sigQ = ws;
    float* Yt   = ws + nBH;
    unsigned short* eKt  = (unsigned short*)(ws + 2 * nBH);
    unsigned short* eKVt = eKt + nBH;
    unsigned short* wqT  = eKVt + nBH;
    unsigned short* wkT  = wqT + (size_t)HD * DIN;
    unsigned short* wvT  = wkT + (size_t)HD * DIN;

    const int M = BATCH * NQ;   // 16384
    dim3 blk(256);

    // 0) weights -> tiled-swizzled bf16
    wtrans_kernel<<<dim3(HD / 64, DIN / 64, 3), blk, 0, stream>>>(
        wq_w, wk_w, wv_w, wqT, wkT, wvT);

    // 1) sigQ = sigmoid(x_q @ wq + b)
    proj_q_mfma<<<dim3(M / TS), blk, 0, stream>>>(x_q, wqT, wq_b, sigQ);

    // 2) eKt/eKVt (bf16, tiled-swizzled) from x_kv
    proj_kv_mfma<<<dim3(M / TS), blk, 0, stream>>>(
        x_kv, wkT, wk_b, wvT, wv_b, eKt, eKVt);

    // 3) Yt = sigQ * (exp(bias)@expKV)/(exp(bias)@expK)
    aft_mfma_kernel<<<dim3(NQ / TS, BATCH), blk, 0, stream>>>(
        bias, eKt, eKVt, sigQ, Yt);

    // 4) out = Yt @ f2_w + f2_b  (fp32, precision guard)
    gemm_bias_kernel<<<dim3(HD / BN, M / BM), blk, 0, stream>>>(
        Yt, f2_w, f2_b, out, M, HD, HD);
}